// Round 1
// baseline (78.991 us; speedup 1.0000x reference)
//
#include <hip/hip_runtime.h>

#define NBODY 8192
#define BLOCK 256
#define SLABS 32
#define JCHUNK (NBODY / SLABS)   // 256
#define SOFT2 1.0e-4f            // 0.01^2

// 2-D decomposition: blockIdx.x selects a 256-body i-tile, blockIdx.y selects
// a 256-body j-slab. Each block stages its j-slab (pos.xyz + mass packed as
// float4) in LDS, accumulates partial accelerations in registers, and
// atomicAdds the 3 components per body. 1024 blocks saturate 256 CUs.
__global__ __launch_bounds__(BLOCK) void nbody_kernel(
    const float* __restrict__ pos, const float* __restrict__ mass,
    float* __restrict__ out) {
  __shared__ float4 tile[JCHUNK];

  const int t = threadIdx.x;
  const int i = blockIdx.x * BLOCK + t;
  const int j0 = blockIdx.y * JCHUNK;

  // Stage j-slab: xyz + mass -> float4 (one per thread; JCHUNK == BLOCK).
  const int j = j0 + t;
  tile[t] = make_float4(pos[j * 3 + 0], pos[j * 3 + 1], pos[j * 3 + 2],
                        mass[j]);

  const float xi = pos[i * 3 + 0];
  const float yi = pos[i * 3 + 1];
  const float zi = pos[i * 3 + 2];

  __syncthreads();

  float ax = 0.f, ay = 0.f, az = 0.f;
#pragma unroll 8
  for (int k = 0; k < JCHUNK; ++k) {
    float4 o = tile[k];  // wave-uniform address -> LDS broadcast, no conflict
    float dx = o.x - xi;
    float dy = o.y - yi;
    float dz = o.z - zi;
    float r2 = fmaf(dx, dx, fmaf(dy, dy, fmaf(dz, dz, SOFT2)));
    float inv = __builtin_amdgcn_rsqf(r2);   // v_rsq_f32
    float w = o.w * (inv * inv * inv);       // m_j * r^-3
    ax = fmaf(w, dx, ax);
    ay = fmaf(w, dy, ay);
    az = fmaf(w, dz, az);
  }

  // 32 slabs contend per address; float atomics are L2-side and cheap here.
  atomicAdd(&out[i * 3 + 0], ax);
  atomicAdd(&out[i * 3 + 1], ay);
  atomicAdd(&out[i * 3 + 2], az);
}

extern "C" void kernel_launch(void* const* d_in, const int* in_sizes, int n_in,
                              void* d_out, int out_size, void* d_ws,
                              size_t ws_size, hipStream_t stream) {
  const float* pos = (const float*)d_in[0];
  const float* mass = (const float*)d_in[1];
  float* out = (float*)d_out;

  // d_out is re-poisoned to 0xAA before every launch; atomics need zeros.
  hipMemsetAsync(d_out, 0, (size_t)out_size * sizeof(float), stream);

  dim3 grid(NBODY / BLOCK, SLABS);
  nbody_kernel<<<grid, BLOCK, 0, stream>>>(pos, mass, out);
}